// Round 3
// baseline (195.170 us; speedup 1.0000x reference)
//
#include <hip/hip_runtime.h>
#include <stdint.h>

#define NUM_ACT 6
#define NUM_OPP 3
#define NUM_SAMPLE 80
#define BATCH 4096
#define DIM 512
#define ACC_STRIDE 98304   /* BATCH*24 */
#define TROWS 32

// ---------------- JAX threefry2x32 (key = (0, 42)) ----------------
__device__ __forceinline__ uint32_t rotl32(uint32_t x, int d) {
  return (x << d) | (x >> (32 - d));
}

__device__ __forceinline__ void tf_round4(uint32_t& x0, uint32_t& x1,
                                          int r0, int r1, int r2, int r3) {
  x0 += x1; x1 = rotl32(x1, r0); x1 ^= x0;
  x0 += x1; x1 = rotl32(x1, r1); x1 ^= x0;
  x0 += x1; x1 = rotl32(x1, r2); x1 ^= x0;
  x0 += x1; x1 = rotl32(x1, r3); x1 ^= x0;
}

__device__ __forceinline__ void threefry2x32(uint32_t k0, uint32_t k1,
                                             uint32_t& x0, uint32_t& x1) {
  const uint32_t ks2 = k0 ^ k1 ^ 0x1BD11BDAu;
  x0 += k0;  x1 += k1;
  tf_round4(x0, x1, 13, 15, 26, 6);  x0 += k1;  x1 += ks2 + 1u;
  tf_round4(x0, x1, 17, 29, 16, 24); x0 += ks2; x1 += k0  + 2u;
  tf_round4(x0, x1, 13, 15, 26, 6);  x0 += k0;  x1 += k1  + 3u;
  tf_round4(x0, x1, 17, 29, 16, 24); x0 += k1;  x1 += ks2 + 4u;
  tf_round4(x0, x1, 13, 15, 26, 6);  x0 += ks2; x1 += k0  + 5u;
}

__device__ __forceinline__ float jax_gumbel(uint32_t flat_idx) {
  uint32_t x0 = 0u, x1 = flat_idx;
  threefry2x32(0u, 42u, x0, x1);
  uint32_t bits = x0 ^ x1;
  uint32_t fb = (bits >> 9) | 0x3f800000u;
  float f = __uint_as_float(fb) - 1.0f;          // [0,1)
  float u = fmaxf(f, 1.17549435e-38f);
  return -__logf(-__logf(u));
}

__device__ __forceinline__ void dot4(float& a, float4 u, float4 v) {
  a = fmaf(u.x, v.x, a); a = fmaf(u.y, v.y, a);
  a = fmaf(u.z, v.z, a); a = fmaf(u.w, v.w, a);
}

// ---------------- K1: split-K tiled GEMM -> per-chunk partials ----------------
// Wcat col c: c<18 -> Wopp[c/6][d][c%6]; c>=18 -> W[d][c-18]
// Block = (tile of 32 rows) x (K-chunk of 512/NCH). 128 threads, 2x3 reg tile.
template<int NCH>
__global__ __launch_bounds__(128) void k1_gemm(
    const float* __restrict__ x, const float* __restrict__ Wopp,
    const float* __restrict__ W, float* __restrict__ part,
    float* __restrict__ ent_slots, int* __restrict__ cnt) {
  constexpr int WIDTH = 512 / NCH;                // 64 (nch=8) / 128 (nch=4)
  constexpr int XSTR = WIDTH + 4;                 // pad: x stride step 8 banks (free),
                                                  //      w stride step 12 banks (free)
  const int tile = blockIdx.x / NCH;
  const int ch = blockIdx.x % NCH;
  const int rowbase = tile * TROWS;
  const int dbase = ch * WIDTH;
  __shared__ float xs[TROWS * XSTR];
  __shared__ float wt[24 * XSTR];
  const int t = threadIdx.x;

  // stage x tile: TROWS x WIDTH floats, coalesced float4
  for (int f = t; f < TROWS * (WIDTH / 4); f += 128) {
    int row = f / (WIDTH / 4), c4 = (f % (WIDTH / 4)) << 2;
    float4 v = *(const float4*)(x + (size_t)(rowbase + row) * DIM + dbase + c4);
    *(float4*)(xs + row * XSTR + c4) = v;
  }
  // stage W chunk transposed: wt[c][dd]
  for (int i = t; i < 24 * WIDTH; i += 128) {
    int c = i % 24, dd = i / 24;
    int d = dbase + dd;
    float v = (c < 18) ? Wopp[(c / 6) * (DIM * 6) + d * 6 + (c % 6)]
                       : W[d * 6 + (c - 18)];
    wt[c * XSTR + dd] = v;
  }
  __syncthreads();

  const int rowg = t >> 3, colg = t & 7;          // 16 x 8 -> 2 rows x 3 cols each
  float acc[2][3] = {{0.f, 0.f, 0.f}, {0.f, 0.f, 0.f}};
  const float* xp = xs + (rowg * 2) * XSTR;
  const float* wp = wt + (colg * 3) * XSTR;
#pragma unroll 4
  for (int dd = 0; dd < WIDTH; dd += 4) {
    float4 x0 = *(const float4*)(xp + dd);
    float4 x1 = *(const float4*)(xp + XSTR + dd);
    float4 w0 = *(const float4*)(wp + dd);
    float4 w1 = *(const float4*)(wp + XSTR + dd);
    float4 w2 = *(const float4*)(wp + 2 * XSTR + dd);
    dot4(acc[0][0], x0, w0); dot4(acc[0][1], x0, w1); dot4(acc[0][2], x0, w2);
    dot4(acc[1][0], x1, w0); dot4(acc[1][1], x1, w1); dot4(acc[1][2], x1, w2);
  }
  const int r0 = rowbase + rowg * 2, c0 = colg * 3;
  float* p = part + (size_t)ch * ACC_STRIDE;
#pragma unroll
  for (int rr = 0; rr < 2; rr++)
#pragma unroll
    for (int cc = 0; cc < 3; cc++)
      p[(r0 + rr) * 24 + c0 + cc] = acc[rr][cc];
  if (blockIdx.x == 0) {                          // zero entropy slots + done counter
    if (t < 64) ent_slots[t] = 0.f;
    if (t == 64) *cnt = 0;
  }
}

// ---------------- K3: softmax+entropy + sample + p2 + agent softmax + output --
__global__ __launch_bounds__(256) void k3_agent(
    const float* __restrict__ part, const float* __restrict__ bopp,
    const float* __restrict__ W, const float* __restrict__ bias,
    float* __restrict__ ent_slots, int* __restrict__ cnt,
    float* __restrict__ dout, int nch) {
  int b = blockIdx.x;
  int t = threadIdx.x;
  __shared__ float s_logits[NUM_OPP][NUM_ACT];
  __shared__ float s_dist[NUM_OPP][NUM_ACT];
  __shared__ float s_xw[NUM_ACT];
  __shared__ float s_bias[NUM_ACT];
  __shared__ float s_W2[NUM_OPP * NUM_ACT][NUM_ACT];
  __shared__ int   s_act[NUM_OPP][NUM_SAMPLE];
  __shared__ float s_prob[NUM_OPP][NUM_SAMPLE];
  __shared__ float s_p1[NUM_SAMPLE];
  __shared__ float s_sum;
  __shared__ float s_wq[NUM_SAMPLE][NUM_ACT];
  __shared__ float s_o[8][NUM_ACT];

  // ---- Phase A (one barrier): per-row logits+softmax+dist+entropy (t<3),
  //      xw/bias (t 64..69), W2 rows (t 128..235) ----
  if (t < 3) {
    float l[NUM_ACT];
#pragma unroll
    for (int a = 0; a < NUM_ACT; a++) {
      float s = bopp[t * 6 + a];
      for (int ch = 0; ch < nch; ch++)
        s += part[ch * ACC_STRIDE + b * 24 + t * 6 + a];
      l[a] = s;
      s_logits[t][a] = s;
    }
    float m = l[0];
#pragma unroll
    for (int a = 1; a < NUM_ACT; a++) m = fmaxf(m, l[a]);
    float e[NUM_ACT], Z = 0.f;
#pragma unroll
    for (int a = 0; a < NUM_ACT; a++) { e[a] = expf(l[a] - m); Z += e[a]; }
    float logZ = logf(Z);
    float H = 0.f;
#pragma unroll
    for (int a = 0; a < NUM_ACT; a++) {
      float pa = e[a] / Z;
      s_dist[t][a] = pa;
      dout[BATCH * NUM_ACT + (t * BATCH + b) * NUM_ACT + a] = pa;
      H -= pa * ((l[a] - m) - logZ);
    }
    atomicAdd(&ent_slots[b & 63], H);
  } else if (t >= 64 && t < 64 + NUM_ACT) {
    int a = t - 64;
    float s = 0.f;
    for (int ch = 0; ch < nch; ch++)
      s += part[ch * ACC_STRIDE + b * 24 + 18 + a];
    s_xw[a] = s;
    s_bias[a] = bias[a];
  } else if (t >= 128 && t < 128 + 108) {
    int i = t - 128;
    s_W2[i / 6][i % 6] = W[DIM * NUM_ACT + i];
  }
  __syncthreads();

  // ---- Sampling: 240 threads, 6 gumbels each ----
  if (t < NUM_OPP * NUM_SAMPLE) {
    int k = t / NUM_SAMPLE, s = t - k * NUM_SAMPLE;
    uint32_t base = ((uint32_t)(k * NUM_SAMPLE + s) * BATCH + (uint32_t)b) * NUM_ACT;
    float best = -3.4e38f;
    int bestA = 0;
#pragma unroll
    for (int a = 0; a < NUM_ACT; a++) {
      float v = s_logits[k][a] + jax_gumbel(base + a);
      if (v > best) { best = v; bestA = a; }      // first max wins
    }
    s_act[k][s] = bestA;
    s_prob[k][s] = s_dist[k][bestA];
  }
  __syncthreads();

  // ---- p1 + sum in one phase (wave 0) ----
  if (t < 64) {
    float v = s_prob[0][t] * s_prob[1][t] * s_prob[2][t];
    s_p1[t] = v;
    if (t < 16) {
      float v2 = s_prob[0][t + 64] * s_prob[1][t + 64] * s_prob[2][t + 64];
      s_p1[t + 64] = v2;
      v += v2;
    }
#pragma unroll
    for (int off = 32; off > 0; off >>= 1) v += __shfl_down(v, off);
    if (t == 0) s_sum = v;
  }
  __syncthreads();

  // ---- per-sample weight + agent softmax ----
  if (t < NUM_SAMPLE) {
    float w = s_p1[t] / s_sum;
    int a0 = s_act[0][t], a1 = s_act[1][t], a2 = s_act[2][t];
    float la[NUM_ACT];
#pragma unroll
    for (int a = 0; a < NUM_ACT; a++)
      la[a] = s_xw[a] + s_W2[a0][a] + s_W2[6 + a1][a] + s_W2[12 + a2][a] + s_bias[a];
    float m = la[0];
#pragma unroll
    for (int a = 1; a < NUM_ACT; a++) m = fmaxf(m, la[a]);
    float e[NUM_ACT], Z = 0.f;
#pragma unroll
    for (int a = 0; a < NUM_ACT; a++) { e[a] = expf(la[a] - m); Z += e[a]; }
#pragma unroll
    for (int a = 0; a < NUM_ACT; a++) s_wq[t][a] = w * (e[a] / Z);
  }
  __syncthreads();

  // ---- column reduction over 80 samples ----
  if (t < 48) {
    int sc = t / 6, a = t - sc * 6;
    float sm = 0.f;
    for (int i = 0; i < 10; i++) sm += s_wq[sc * 10 + i][a];
    s_o[sc][a] = sm;
  }
  __syncthreads();
  if (t < NUM_ACT) {
    float sm = 0.f;
#pragma unroll
    for (int sc = 0; sc < 8; sc++) sm += s_o[sc][t];
    dout[b * NUM_ACT + t] = sm;
  }

  // ---- last block writes entropy scalar ----
  if (t == 0) {
    __threadfence();
    if (atomicAdd(cnt, 1) == BATCH - 1) {
      float s = 0.f;
      for (int i = 0; i < 64; i++) s += atomicAdd(&ent_slots[i], 0.0f);
      dout[BATCH * NUM_ACT + NUM_OPP * BATCH * NUM_ACT] = s * (1.0f / 12288.0f);
    }
  }
}

extern "C" void kernel_launch(void* const* d_in, const int* in_sizes, int n_in,
                              void* d_out, int out_size, void* d_ws, size_t ws_size,
                              hipStream_t stream) {
  const float* x    = (const float*)d_in[0];
  const float* Wopp = (const float*)d_in[1];
  const float* bopp = (const float*)d_in[2];
  const float* W    = (const float*)d_in[3];
  const float* bias = (const float*)d_in[4];
  float* out = (float*)d_out;
  float* part = (float*)d_ws;

  size_t need8 = ((size_t)8 * ACC_STRIDE + 64 + 1) * sizeof(float);
  int nch = (ws_size >= need8) ? 8 : 4;
  float* ent_slots = part + (size_t)nch * ACC_STRIDE;
  int* cnt = (int*)(ent_slots + 64);

  if (nch == 8) k1_gemm<8><<<128 * 8, 128, 0, stream>>>(x, Wopp, W, part, ent_slots, cnt);
  else          k1_gemm<4><<<128 * 4, 128, 0, stream>>>(x, Wopp, W, part, ent_slots, cnt);
  k3_agent<<<BATCH, 256, 0, stream>>>(part, bopp, W, bias, ent_slots, cnt, out, nch);
}

// Round 4
// 100.765 us; speedup vs baseline: 1.9369x; 1.9369x over previous
//
#include <hip/hip_runtime.h>
#include <stdint.h>

#define NUM_ACT 6
#define NUM_OPP 3
#define NUM_SAMPLE 80
#define BATCH 4096
#define DIM 512
#define ACC_STRIDE 98304   /* BATCH*24 */
#define TROWS 32

// ---------------- JAX threefry2x32 (key = (0, 42)) ----------------
__device__ __forceinline__ uint32_t rotl32(uint32_t x, int d) {
  return (x << d) | (x >> (32 - d));
}

__device__ __forceinline__ void tf_round4(uint32_t& x0, uint32_t& x1,
                                          int r0, int r1, int r2, int r3) {
  x0 += x1; x1 = rotl32(x1, r0); x1 ^= x0;
  x0 += x1; x1 = rotl32(x1, r1); x1 ^= x0;
  x0 += x1; x1 = rotl32(x1, r2); x1 ^= x0;
  x0 += x1; x1 = rotl32(x1, r3); x1 ^= x0;
}

__device__ __forceinline__ void threefry2x32(uint32_t k0, uint32_t k1,
                                             uint32_t& x0, uint32_t& x1) {
  const uint32_t ks2 = k0 ^ k1 ^ 0x1BD11BDAu;
  x0 += k0;  x1 += k1;
  tf_round4(x0, x1, 13, 15, 26, 6);  x0 += k1;  x1 += ks2 + 1u;
  tf_round4(x0, x1, 17, 29, 16, 24); x0 += ks2; x1 += k0  + 2u;
  tf_round4(x0, x1, 13, 15, 26, 6);  x0 += k0;  x1 += k1  + 3u;
  tf_round4(x0, x1, 17, 29, 16, 24); x0 += k1;  x1 += ks2 + 4u;
  tf_round4(x0, x1, 13, 15, 26, 6);  x0 += ks2; x1 += k0  + 5u;
}

__device__ __forceinline__ float jax_gumbel(uint32_t flat_idx) {
  uint32_t x0 = 0u, x1 = flat_idx;
  threefry2x32(0u, 42u, x0, x1);
  uint32_t bits = x0 ^ x1;
  uint32_t fb = (bits >> 9) | 0x3f800000u;
  float f = __uint_as_float(fb) - 1.0f;          // [0,1)
  float u = fmaxf(f, 1.17549435e-38f);
  return -__logf(-__logf(u));
}

__device__ __forceinline__ void dot4(float& a, float4 u, float4 v) {
  a = fmaf(u.x, v.x, a); a = fmaf(u.y, v.y, a);
  a = fmaf(u.z, v.z, a); a = fmaf(u.w, v.w, a);
}

// ---------------- K1: split-K tiled GEMM -> per-chunk partials ----------------
// Wcat col c: c<18 -> Wopp[c/6][d][c%6]; c>=18 -> W[d][c-18]
// Block = (tile of 32 rows) x (K-chunk of 512/NCH). 128 threads, 2x3 reg tile.
// NO device fences anywhere (gfx950 agent fences force L2 writebacks - 126us
// regression in R3). Cross-kernel ordering via kernel boundaries only.
template<int NCH>
__global__ __launch_bounds__(128) void k1_gemm(
    const float* __restrict__ x, const float* __restrict__ Wopp,
    const float* __restrict__ W, float* __restrict__ part,
    float* __restrict__ ws_ent) {
  constexpr int WIDTH = 512 / NCH;                // 64 (nch=8) / 128 (nch=4)
  constexpr int XSTR = WIDTH + 4;                 // pad: x step 8 banks (free 2-way),
                                                  //      w step 12 banks (distinct)
  const int tile = blockIdx.x / NCH;
  const int ch = blockIdx.x % NCH;
  const int rowbase = tile * TROWS;
  const int dbase = ch * WIDTH;
  __shared__ float xs[TROWS * XSTR];
  __shared__ float wt[24 * XSTR];
  const int t = threadIdx.x;

  // stage x tile: TROWS x WIDTH floats, coalesced float4
  for (int f = t; f < TROWS * (WIDTH / 4); f += 128) {
    int row = f / (WIDTH / 4), c4 = (f % (WIDTH / 4)) << 2;
    float4 v = *(const float4*)(x + (size_t)(rowbase + row) * DIM + dbase + c4);
    *(float4*)(xs + row * XSTR + c4) = v;
  }
  // stage W chunk transposed: wt[c][dd]
  for (int i = t; i < 24 * WIDTH; i += 128) {
    int c = i % 24, dd = i / 24;
    int d = dbase + dd;
    float v = (c < 18) ? Wopp[(c / 6) * (DIM * 6) + d * 6 + (c % 6)]
                       : W[d * 6 + (c - 18)];
    wt[c * XSTR + dd] = v;
  }
  __syncthreads();

  const int rowg = t >> 3, colg = t & 7;          // 16 x 8 -> 2 rows x 3 cols each
  float acc[2][3] = {{0.f, 0.f, 0.f}, {0.f, 0.f, 0.f}};
  const float* xp = xs + (rowg * 2) * XSTR;
  const float* wp = wt + (colg * 3) * XSTR;
#pragma unroll 4
  for (int dd = 0; dd < WIDTH; dd += 4) {
    float4 x0 = *(const float4*)(xp + dd);
    float4 x1 = *(const float4*)(xp + XSTR + dd);
    float4 w0 = *(const float4*)(wp + dd);
    float4 w1 = *(const float4*)(wp + XSTR + dd);
    float4 w2 = *(const float4*)(wp + 2 * XSTR + dd);
    dot4(acc[0][0], x0, w0); dot4(acc[0][1], x0, w1); dot4(acc[0][2], x0, w2);
    dot4(acc[1][0], x1, w0); dot4(acc[1][1], x1, w1); dot4(acc[1][2], x1, w2);
  }
  const int r0 = rowbase + rowg * 2, c0 = colg * 3;
  float* p = part + (size_t)ch * ACC_STRIDE;
#pragma unroll
  for (int rr = 0; rr < 2; rr++)
#pragma unroll
    for (int cc = 0; cc < 3; cc++)
      p[(r0 + rr) * 24 + c0 + cc] = acc[rr][cc];
  if (blockIdx.x == 0 && t == 0) ws_ent[0] = 0.f;  // visible to k2 at kernel boundary
}

// ---------------- K2: softmax -> dist (d_out) + entropy atomic ----------------
template<int NCH>
__global__ __launch_bounds__(256) void k2_softmax(
    const float* __restrict__ part, const float* __restrict__ bopp,
    float* __restrict__ dout, float* __restrict__ ws_ent) {
  int row = blockIdx.x * 256 + threadIdx.x;       // 12288 = 3*4096 rows
  int k = row >> 12, b = row & 4095;
  float l[NUM_ACT];
#pragma unroll
  for (int a = 0; a < NUM_ACT; a++) {
    float s = bopp[k * 6 + a];
#pragma unroll
    for (int ch = 0; ch < NCH; ch++)
      s += part[ch * ACC_STRIDE + b * 24 + k * 6 + a];
    l[a] = s;
  }
  float m = l[0];
#pragma unroll
  for (int a = 1; a < NUM_ACT; a++) m = fmaxf(m, l[a]);
  float e[NUM_ACT], Z = 0.f;
#pragma unroll
  for (int a = 0; a < NUM_ACT; a++) { e[a] = expf(l[a] - m); Z += e[a]; }
  float logZ = logf(Z);
  float H = 0.f;
#pragma unroll
  for (int a = 0; a < NUM_ACT; a++) {
    float pa = e[a] / Z;
    dout[BATCH * NUM_ACT + row * NUM_ACT + a] = pa;
    H -= pa * ((l[a] - m) - logZ);
  }
#pragma unroll
  for (int off = 32; off > 0; off >>= 1) H += __shfl_down(H, off);
  if ((threadIdx.x & 63) == 0) atomicAdd(ws_ent, H);
}

// ---------------- K3: sample + p2 + agent softmax + output ----------------
template<int NCH>
__global__ __launch_bounds__(256) void k3_agent(
    const float* __restrict__ part, const float* __restrict__ bopp,
    const float* __restrict__ W, const float* __restrict__ bias,
    const float* __restrict__ ws_ent, float* __restrict__ dout) {
  int b = blockIdx.x;
  int t = threadIdx.x;
  __shared__ float s_logits[NUM_OPP][NUM_ACT];
  __shared__ float s_dist[NUM_OPP][NUM_ACT];
  __shared__ float s_xw[NUM_ACT];
  __shared__ float s_bias[NUM_ACT];
  __shared__ float s_W2[NUM_OPP * NUM_ACT][NUM_ACT];
  __shared__ int   s_act[NUM_OPP][NUM_SAMPLE];
  __shared__ float s_prob[NUM_OPP][NUM_SAMPLE];
  __shared__ float s_p1[NUM_SAMPLE];
  __shared__ float s_sum;
  __shared__ float s_wq[NUM_SAMPLE][NUM_ACT];
  __shared__ float s_o[8][NUM_ACT];

  // ---- Phase A (one barrier): disjoint thread ranges ----
  if (t < 18) {
    int k = t / 6, a = t - k * 6;
    float s = bopp[t];
#pragma unroll
    for (int ch = 0; ch < NCH; ch++)
      s += part[ch * ACC_STRIDE + b * 24 + t];    // c = k*6+a = t
    s_logits[k][a] = s;
    s_dist[k][a] = dout[BATCH * NUM_ACT + (k * BATCH + b) * NUM_ACT + a];
  } else if (t >= 64 && t < 64 + NUM_ACT) {
    int a = t - 64;
    float s = 0.f;
#pragma unroll
    for (int ch = 0; ch < NCH; ch++)
      s += part[ch * ACC_STRIDE + b * 24 + 18 + a];
    s_xw[a] = s;
    s_bias[a] = bias[a];
  } else if (t >= 128 && t < 128 + 108) {
    int i = t - 128;
    s_W2[i / 6][i % 6] = W[DIM * NUM_ACT + i];
  }
  __syncthreads();

  // ---- Sampling: 240 threads, 6 gumbels each ----
  if (t < NUM_OPP * NUM_SAMPLE) {
    int k = t / NUM_SAMPLE, s = t - k * NUM_SAMPLE;
    uint32_t base = ((uint32_t)(k * NUM_SAMPLE + s) * BATCH + (uint32_t)b) * NUM_ACT;
    float best = -3.4e38f;
    int bestA = 0;
#pragma unroll
    for (int a = 0; a < NUM_ACT; a++) {
      float v = s_logits[k][a] + jax_gumbel(base + a);
      if (v > best) { best = v; bestA = a; }      // first max wins
    }
    s_act[k][s] = bestA;
    s_prob[k][s] = s_dist[k][bestA];
  }
  __syncthreads();

  // ---- p1 + sum in one phase (wave 0) ----
  if (t < 64) {
    float v = s_prob[0][t] * s_prob[1][t] * s_prob[2][t];
    s_p1[t] = v;
    if (t < 16) {
      float v2 = s_prob[0][t + 64] * s_prob[1][t + 64] * s_prob[2][t + 64];
      s_p1[t + 64] = v2;
      v += v2;
    }
#pragma unroll
    for (int off = 32; off > 0; off >>= 1) v += __shfl_down(v, off);
    if (t == 0) s_sum = v;
  }
  __syncthreads();

  // ---- per-sample weight + agent softmax ----
  if (t < NUM_SAMPLE) {
    float w = s_p1[t] / s_sum;
    int a0 = s_act[0][t], a1 = s_act[1][t], a2 = s_act[2][t];
    float la[NUM_ACT];
#pragma unroll
    for (int a = 0; a < NUM_ACT; a++)
      la[a] = s_xw[a] + s_W2[a0][a] + s_W2[6 + a1][a] + s_W2[12 + a2][a] + s_bias[a];
    float m = la[0];
#pragma unroll
    for (int a = 1; a < NUM_ACT; a++) m = fmaxf(m, la[a]);
    float e[NUM_ACT], Z = 0.f;
#pragma unroll
    for (int a = 0; a < NUM_ACT; a++) { e[a] = expf(la[a] - m); Z += e[a]; }
#pragma unroll
    for (int a = 0; a < NUM_ACT; a++) s_wq[t][a] = w * (e[a] / Z);
  }
  __syncthreads();

  // ---- column reduction over 80 samples ----
  if (t < 48) {
    int sc = t / 6, a = t - sc * 6;
    float sm = 0.f;
#pragma unroll
    for (int i = 0; i < 10; i++) sm += s_wq[sc * 10 + i][a];
    s_o[sc][a] = sm;
  }
  __syncthreads();
  if (t < NUM_ACT) {
    float sm = 0.f;
#pragma unroll
    for (int sc = 0; sc < 8; sc++) sm += s_o[sc][t];
    dout[b * NUM_ACT + t] = sm;
  }
  if (b == 0 && t == 255) {
    // ws_ent complete: k2 finished at kernel boundary before k3 started
    dout[BATCH * NUM_ACT + NUM_OPP * BATCH * NUM_ACT] = ws_ent[0] * (1.0f / 12288.0f);
  }
}

extern "C" void kernel_launch(void* const* d_in, const int* in_sizes, int n_in,
                              void* d_out, int out_size, void* d_ws, size_t ws_size,
                              hipStream_t stream) {
  const float* x    = (const float*)d_in[0];
  const float* Wopp = (const float*)d_in[1];
  const float* bopp = (const float*)d_in[2];
  const float* W    = (const float*)d_in[3];
  const float* bias = (const float*)d_in[4];
  float* out = (float*)d_out;
  float* part = (float*)d_ws;

  size_t need8 = ((size_t)8 * ACC_STRIDE + 1) * sizeof(float);
  if (ws_size >= need8) {
    float* ws_ent = part + (size_t)8 * ACC_STRIDE;
    k1_gemm<8><<<128 * 8, 128, 0, stream>>>(x, Wopp, W, part, ws_ent);
    k2_softmax<8><<<48, 256, 0, stream>>>(part, bopp, out, ws_ent);
    k3_agent<8><<<BATCH, 256, 0, stream>>>(part, bopp, W, bias, ws_ent, out);
  } else {
    float* ws_ent = part + (size_t)4 * ACC_STRIDE;
    k1_gemm<4><<<128 * 4, 128, 0, stream>>>(x, Wopp, W, part, ws_ent);
    k2_softmax<4><<<48, 256, 0, stream>>>(part, bopp, out, ws_ent);
    k3_agent<4><<<BATCH, 256, 0, stream>>>(part, bopp, W, bias, ws_ent, out);
  }
}